// Round 2
// baseline (81.758 us; speedup 1.0000x reference)
//
#include <hip/hip_runtime.h>
#include <math.h>

// DiffractiveLayer: out[j] = sum_i modes[i] * G[i,j] * dA  with
// G[i,j] = f(a_i - c_j, b_i - d_j)  -> 2D complex convolution with a
// (2N-1)x(2N-1) tap table. Precompute taps (double precision), then
// direct convolution in fp32 out of LDS.
//
// Output layout is dispatched on out_size:
//   out_size == N*N     -> harness kept only the real part (astype)
//   out_size == 2*N*N   -> complex64 viewed as interleaved float32 pairs

#define NN 96
#define M (NN*NN)
#define GH 191          // 2N-1 tap rows/cols
#define GW 192          // padded row stride (float2 elements)

__device__ float2 g_G[GH * GW];     // tap table, dA folded in
__device__ float2 g_modes[M];       // exp(j*w)*x

__global__ __launch_bounds__(256) void precompute_kernel(
    const float* __restrict__ x, const float* __restrict__ w,
    const float* __restrict__ xc, const float* __restrict__ yc) {
  const double DZ     = 1e-5;
  const double LAMBDA = 1.55e-6;
  const double PI     = 3.14159265358979323846;
  const double K      = 2.0 * PI / LAMBDA;
  const double DA     = 1.55e-6 * 1.55e-6;

  int idx = blockIdx.x * 256 + threadIdx.x;
  if (idx < GH * GH) {
    int u = idx / GH - (NN - 1);
    int v = idx % GH - (NN - 1);
    int au = u < 0 ? -u : u;
    int av = v < 0 ? -v : v;
    // use the fp32-rounded input coords (matches reference's systematic
    // rounding); sign irrelevant since only squares enter r.
    double dx = (double)xc[au] - (double)xc[0];
    double dy = (double)yc[av] - (double)yc[0];
    double r2 = dx * dx + dy * dy + DZ * DZ;
    double r  = sqrt(r2);
    double amp = DZ / r2 * DA;                // dz/r^2 * dA
    double A = amp / (2.0 * PI * r);
    double B = amp / LAMBDA;
    double s, c;
    sincos(K * r, &s, &c);
    // (A - jB)(c + js) = (A c + B s) + j(A s - B c)
    g_G[(u + NN - 1) * GW + (v + NN - 1)] =
        make_float2((float)(A * c + B * s), (float)(A * s - B * c));
  } else if (idx < GH * GH + M) {
    int i = idx - GH * GH;
    double s, c;
    sincos((double)w[i], &s, &c);
    double xv = (double)x[i];
    g_modes[i] = make_float2((float)(c * xv), (float)(s * xv));
  }
}

// grid: (96 output rows c, 8 source-row chunks), block: 192 threads.
// Each block: a in [a0, a0+12), all b, all 96 outputs d of row c.
// Thread (d = t%96, h = t/96) accumulates a = a0+h, a0+h+2, ...
__global__ __launch_bounds__(192) void conv_kernel(float* __restrict__ out,
                                                   int interleaved) {
  int c  = blockIdx.x;
  int a0 = blockIdx.y * 12;
  int t  = threadIdx.x;

  __shared__ float2 s_modes[12 * NN];   // 9 KB
  __shared__ float2 s_G[12 * GW];       // 18 KB
  __shared__ float2 s_red[NN];

  // stage modes rows a0..a0+11  (12*96 = 1152 = 6*192)
  #pragma unroll
  for (int k = 0; k < 6; ++k)
    s_modes[k * 192 + t] = g_modes[a0 * NN + k * 192 + t];
  // stage G rows (a - c + 95) for the 12 a values, full padded width
  #pragma unroll
  for (int k = 0; k < 12; ++k)
    s_G[k * GW + t] = g_G[(a0 + k - c + (NN - 1)) * GW + t];
  __syncthreads();

  int d = t % NN;
  int h = t / NN;
  float re = 0.f, im = 0.f;
  for (int ai = h; ai < 12; ai += 2) {
    const float2* __restrict__ mrow = s_modes + ai * NN;
    const float2* __restrict__ grow = s_G + ai * GW + (NN - 1 - d);
    #pragma unroll 8
    for (int b = 0; b < NN; ++b) {
      float2 m  = mrow[b];   // wave-broadcast
      float2 gv = grow[b];
      re = fmaf(m.x, gv.x, re);
      re = fmaf(-m.y, gv.y, re);
      im = fmaf(m.x, gv.y, im);
      im = fmaf(m.y, gv.x, im);
    }
  }

  if (h == 1) s_red[d] = make_float2(re, im);
  __syncthreads();
  if (h == 0) {
    re += s_red[d].x;
    im += s_red[d].y;
    int j = c * NN + d;
    if (interleaved) {
      atomicAdd(out + 2 * j,     re);
      atomicAdd(out + 2 * j + 1, im);
    } else {
      atomicAdd(out + j, re);      // harness kept only the real part
    }
  }
}

extern "C" void kernel_launch(void* const* d_in, const int* in_sizes, int n_in,
                              void* d_out, int out_size, void* d_ws, size_t ws_size,
                              hipStream_t stream) {
  const float* x  = (const float*)d_in[0];
  const float* w  = (const float*)d_in[1];
  const float* xc = (const float*)d_in[2];
  const float* yc = (const float*)d_in[3];
  float* out = (float*)d_out;

  // zero accumulator target
  hipMemsetAsync(d_out, 0, (size_t)out_size * sizeof(float), stream);

  int total = GH * GH + M;
  precompute_kernel<<<(total + 255) / 256, 256, 0, stream>>>(x, w, xc, yc);

  int interleaved = (out_size >= 2 * M) ? 1 : 0;
  conv_kernel<<<dim3(NN, 8), 192, 0, stream>>>(out, interleaved);
}

// Round 3
// 76.828 us; speedup vs baseline: 1.0642x; 1.0642x over previous
//
#include <hip/hip_runtime.h>
#include <math.h>

// DiffractiveLayer: out[j] = sum_i modes[i] * G[i,j] * dA  with
// G[i,j] = f(a_i - c_j, b_i - d_j)  -> 2D complex convolution with a
// (2N-1)x(2N-1) tap table. Precompute taps (double precision for phase:
// k*r up to ~843 rad), then register-blocked direct convolution in fp32.
//
// Output layout dispatched on out_size:
//   out_size == N*N   -> real part only
//   out_size >= 2*N*N -> complex64 as interleaved float32 pairs

#define NN 96
#define M (NN*NN)
#define GH 191           // 2N-1 tap rows/cols
#define GWG 192          // global tap row stride (float2)
#define GW2 200          // LDS tap row stride (float2), slack for ring overrun
#define MW2 104          // LDS modes row stride (float2), de-banked

__device__ float2 g_G[GH * GWG];    // tap table, dA folded in
__device__ float2 g_modes[M];       // exp(j*w)*x

__global__ __launch_bounds__(256) void precompute_kernel(
    const float* __restrict__ x, const float* __restrict__ w,
    const float* __restrict__ xc, const float* __restrict__ yc) {
  const double DZ     = 1e-5;
  const double LAMBDA = 1.55e-6;
  const double PI     = 3.14159265358979323846;
  const double K      = 2.0 * PI / LAMBDA;
  const double DA     = 1.55e-6 * 1.55e-6;

  int idx = blockIdx.x * 256 + threadIdx.x;
  if (idx < GH * GH) {
    int u = idx / GH - (NN - 1);
    int v = idx % GH - (NN - 1);
    int au = u < 0 ? -u : u;
    int av = v < 0 ? -v : v;
    // fp32-rounded input coords match the reference's systematic rounding
    double dx = (double)xc[au] - (double)xc[0];
    double dy = (double)yc[av] - (double)yc[0];
    double r2 = dx * dx + dy * dy + DZ * DZ;
    double r  = sqrt(r2);
    double amp = DZ / r2 * DA;
    double A = amp / (2.0 * PI * r);
    double B = amp / LAMBDA;
    double s, c;
    sincos(K * r, &s, &c);
    // (A - jB)(c + js) = (A c + B s) + j(A s - B c)
    g_G[(u + NN - 1) * GWG + (v + NN - 1)] =
        make_float2((float)(A * c + B * s), (float)(A * s - B * c));
  } else if (idx < GH * GH + M) {
    int i = idx - GH * GH;
    float s, c;
    __sincosf(0.0f, &s, &c);  // (touch to keep fast path; real below)
    sincosf(w[i], &s, &c);
    float xv = x[i];
    g_modes[i] = make_float2(c * xv, s * xv);
  }
}

// grid: (96 output rows c, 12 source-row chunks of 8), block 192.
// Thread t: q = t%24 -> outputs d = 4q..4q+3;  h = t/24 -> source row a0+h.
// Register ring of 3 float4 (6 taps) -> 1 new b128 tap read per 2 b-steps.
__global__ __launch_bounds__(192) void conv_kernel(float* __restrict__ out,
                                                   int interleaved) {
  int c  = blockIdx.x;
  int a0 = blockIdx.y * 8;
  int t  = threadIdx.x;

  __shared__ float2 s_modes[8 * MW2];      // 8 rows x 96 (stride 104)
  __shared__ float2 s_G[8 * GW2 + 8];      // 8 rows x 192 (stride 200) + slack
  __shared__ float2 s_red[8 * NN];

  // stage modes: 8 rows x 48 float4 = 384 float4, 2 per thread
  {
    float4* dst = (float4*)s_modes;
    const float4* src = (const float4*)(g_modes + a0 * NN);
    #pragma unroll
    for (int k = 0; k < 2; ++k) {
      int idx = k * 192 + t;            // 0..383
      int row = idx / 48, col = idx % 48;
      ((float4*)(s_modes + row * MW2))[col] = src[row * 48 + col];
      (void)dst;
    }
  }
  // stage taps: 8 rows x 96 float4 = 768 float4, 4 per thread
  #pragma unroll
  for (int k = 0; k < 4; ++k) {
    int idx = k * 192 + t;              // 0..767
    int row = idx / 96, col = idx % 96;
    const float4* src = (const float4*)(g_G + (a0 + row - c + (NN - 1)) * GWG);
    ((float4*)(s_G + row * GW2))[col] = src[col];
  }
  __syncthreads();

  int q = t % 24;
  int h = t / 24;
  int base = 92 - 4 * q;                // even, >= 0
  const float4* Grow = (const float4*)(s_G + h * GW2);
  const float4* Mrow = (const float4*)(s_modes + h * MW2);
  int gb = base >> 1;

  float4 g0 = Grow[gb];
  float4 g1 = Grow[gb + 1];
  float4 g2 = Grow[gb + 2];
  float2 a0c = {0.f, 0.f}, a1c = {0.f, 0.f}, a2c = {0.f, 0.f}, a3c = {0.f, 0.f};

#define CFMA(acc, mr, mi, gr, gi)                 \
  acc.x = fmaf(mr, gr, acc.x);                    \
  acc.x = fmaf(-(mi), gi, acc.x);                 \
  acc.y = fmaf(mr, gi, acc.y);                    \
  acc.y = fmaf(mi, gr, acc.y)

  for (int b = 0; b < NN; b += 2) {
    float4 mm = Mrow[b >> 1];   // m[b]=(x,y)  m[b+1]=(z,w)
    // window slot w = idx - (b+base); output e uses w=3-e (at b), 4-e (at b+1)
    CFMA(a0c, mm.x, mm.y, g1.z, g1.w);
    CFMA(a0c, mm.z, mm.w, g2.x, g2.y);
    CFMA(a1c, mm.x, mm.y, g1.x, g1.y);
    CFMA(a1c, mm.z, mm.w, g1.z, g1.w);
    CFMA(a2c, mm.x, mm.y, g0.z, g0.w);
    CFMA(a2c, mm.z, mm.w, g1.x, g1.y);
    CFMA(a3c, mm.x, mm.y, g0.x, g0.y);
    CFMA(a3c, mm.z, mm.w, g0.z, g0.w);
    g0 = g1;
    g1 = g2;
    g2 = Grow[gb + 3 + (b >> 1)];   // next pair; slack covers final overrun
  }
#undef CFMA

  int dbase = 4 * q;
  s_red[h * NN + dbase + 0] = a0c;
  s_red[h * NN + dbase + 1] = a1c;
  s_red[h * NN + dbase + 2] = a2c;
  s_red[h * NN + dbase + 3] = a3c;
  __syncthreads();

  if (t < NN) {
    float re = 0.f, im = 0.f;
    #pragma unroll
    for (int hh = 0; hh < 8; ++hh) {
      re += s_red[hh * NN + t].x;
      im += s_red[hh * NN + t].y;
    }
    int j = c * NN + t;
    if (interleaved) {
      atomicAdd(out + 2 * j,     re);
      atomicAdd(out + 2 * j + 1, im);
    } else {
      atomicAdd(out + j, re);
    }
  }
}

extern "C" void kernel_launch(void* const* d_in, const int* in_sizes, int n_in,
                              void* d_out, int out_size, void* d_ws, size_t ws_size,
                              hipStream_t stream) {
  const float* x  = (const float*)d_in[0];
  const float* w  = (const float*)d_in[1];
  const float* xc = (const float*)d_in[2];
  const float* yc = (const float*)d_in[3];
  float* out = (float*)d_out;

  hipMemsetAsync(d_out, 0, (size_t)out_size * sizeof(float), stream);

  int total = GH * GH + M;
  precompute_kernel<<<(total + 255) / 256, 256, 0, stream>>>(x, w, xc, yc);

  int interleaved = (out_size >= 2 * M) ? 1 : 0;
  conv_kernel<<<dim3(NN, 12), 192, 0, stream>>>(out, interleaved);
}